// Round 13
// baseline (190.216 us; speedup 1.0000x reference)
//
#include <hip/hip_runtime.h>
#include <hip/hip_bf16.h>

typedef __attribute__((ext_vector_type(8))) short short8;     // 8 bf16 (MFMA A/B frag, K=32)
typedef __attribute__((ext_vector_type(4))) float float4v;    // MFMA C/D frag

// ---------------------------------------------------------------------------
// Fused: fp32->bf16 convert of x (blocks 0..4095) + RoPE table (blocks 4096+).
// tab[s][p] = (cos,sin)(s * 10000^(-p/32)) for s<2048, p<32 — 512 KB,
// L2-resident for qkv_prep (removes 2M sincosf + 1M powf from the hot path).
// ---------------------------------------------------------------------------
__global__ __launch_bounds__(256) void cvt_and_table(
    const float* __restrict__ in, __hip_bfloat16* __restrict__ out,
    float2* __restrict__ tab) {
  if (blockIdx.x >= 4096) {
    const int i = (blockIdx.x - 4096) * 256 + threadIdx.x;   // 65536
    const int s = i >> 5, p = i & 31;
    const float freq = powf(10000.f, -(float)(p * 2) / 64.f);
    float sn, cs;
    sincosf((float)s * freq, &sn, &cs);
    tab[i] = make_float2(cs, sn);
    return;
  }
  const int i = blockIdx.x * 256 + threadIdx.x;
  const float4 v = *(const float4*)(in + (size_t)i * 4);
  __hip_bfloat16 o[4];
  o[0] = __float2bfloat16(v.x); o[1] = __float2bfloat16(v.y);
  o[2] = __float2bfloat16(v.z); o[3] = __float2bfloat16(v.w);
  *(uint2*)(out + (size_t)i * 4) = *(const uint2*)o;
}

// ---------------------------------------------------------------------------
// Fused weight transposes: z=0 -> WqkvT (1024x3072 -> 3072x1024),
// z=1 -> WoutT (1024x1024 -> 1024x1024). fp32 in, bf16 out.
// ---------------------------------------------------------------------------
__global__ __launch_bounds__(256) void prep_weights(
    const float* __restrict__ Wqkv, const float* __restrict__ Wout,
    __hip_bfloat16* __restrict__ WqkvT, __hip_bfloat16* __restrict__ WoutT) {
  const int z = blockIdx.z;
  if (z == 1 && blockIdx.x >= 32) return;
  const float* in = z ? Wout : Wqkv;
  __hip_bfloat16* out = z ? WoutT : WqkvT;
  const int R = 1024, C = z ? 1024 : 3072;
  __shared__ __hip_bfloat16 tile[32][33];
  const int c0 = blockIdx.x * 32, r0 = blockIdx.y * 32;
  const int tx = threadIdx.x & 31, ty = threadIdx.x >> 5;  // ty 0..7
  #pragma unroll
  for (int i = ty; i < 32; i += 8)
    tile[i][tx] = __float2bfloat16(in[(size_t)(r0 + i) * C + (c0 + tx)]);
  __syncthreads();
  #pragma unroll
  for (int i = ty; i < 32; i += 8)
    out[(size_t)(c0 + i) * R + (r0 + tx)] = tile[tx][i];
}

// ---------------------------------------------------------------------------
// gemm_bt: C (MxN, OutT) = A (MxK, row-major bf16) @ Bt^T  (Bt is NxK bf16)
// 128xBN tile, BK=64, 256 threads = 4 waves, global_load_lds width=16 staging,
// stride-64 LDS + XOR chunk swizzle (r6-verified) — now DOUBLE-BUFFERED with
// prefetch-after-barrier (the r7 recipe that took attention 113 -> 45 µs):
// one barrier per K-iter; DMA(kt+1) issued after the barrier flies during
// kt's compute, so the vmcnt(0) drain at the next barrier is near-free.
// LDS: BN=128 -> 64 KB (2 blocks/CU), BN=64 -> 48 KB (3 blocks/CU).
// ---------------------------------------------------------------------------
template <typename OutT, int BN>
__global__ __launch_bounds__(256) void gemm_bt(
    const __hip_bfloat16* __restrict__ A,
    const __hip_bfloat16* __restrict__ Bt,
    OutT* __restrict__ C,
    int M, int N, int K) {
  __shared__ __hip_bfloat16 lA[2][128][64];
  __shared__ __hip_bfloat16 lB[2][BN][64];
  constexpr int NJ = BN / 32;                    // j-tiles of 16 per wave
  const int t = threadIdx.x;
  const int lane = t & 63, wave = t >> 6;
  const int quad = lane >> 4, ln = lane & 15;
  const int m0 = blockIdx.y * 128, n0 = blockIdx.x * BN;
  const int wm = (wave >> 1) * 64, wn = (wave & 1) * (BN / 2);
  const int srow = lane >> 3;                    // 0..7
  const int schunk = ((lane & 7) ^ srow) * 8;    // swizzled elem offset

  float4v acc[4][NJ];
  #pragma unroll
  for (int i = 0; i < 4; ++i)
    #pragma unroll
    for (int j = 0; j < NJ; ++j)
      acc[i][j] = (float4v){0.f, 0.f, 0.f, 0.f};

  // stage kt=0 into buf 0
  #pragma unroll
  for (int q = 0; q < 4; ++q) {
    const int rbase = wave * 32 + q * 8;
    __builtin_amdgcn_global_load_lds(
        (const __attribute__((address_space(1))) void*)
            (A + (size_t)(m0 + rbase + srow) * K + schunk),
        (__attribute__((address_space(3))) void*)&lA[0][rbase][0], 16, 0, 0);
  }
  #pragma unroll
  for (int g = 0; g < BN / 32; ++g) {
    const int rbase = wave * (BN / 4) + g * 8;
    __builtin_amdgcn_global_load_lds(
        (const __attribute__((address_space(1))) void*)
            (Bt + (size_t)(n0 + rbase + srow) * K + schunk),
        (__attribute__((address_space(3))) void*)&lB[0][rbase][0], 16, 0, 0);
  }

  const int nk = K >> 6;
  for (int ki = 0; ki < nk; ++ki) {
    const int buf = ki & 1;
    __syncthreads();   // drains DMA(ki) (in flight one compute phase); frees buf^1

    if (ki + 1 < nk) {   // prefetch ki+1 into the other buffer — after barrier
      const int kn = (ki + 1) << 6;
      #pragma unroll
      for (int q = 0; q < 4; ++q) {
        const int rbase = wave * 32 + q * 8;
        __builtin_amdgcn_global_load_lds(
            (const __attribute__((address_space(1))) void*)
                (A + (size_t)(m0 + rbase + srow) * K + kn + schunk),
            (__attribute__((address_space(3))) void*)&lA[buf ^ 1][rbase][0], 16, 0, 0);
      }
      #pragma unroll
      for (int g = 0; g < BN / 32; ++g) {
        const int rbase = wave * (BN / 4) + g * 8;
        __builtin_amdgcn_global_load_lds(
            (const __attribute__((address_space(1))) void*)
                (Bt + (size_t)(n0 + rbase + srow) * K + kn + schunk),
            (__attribute__((address_space(3))) void*)&lB[buf ^ 1][rbase][0], 16, 0, 0);
      }
    }

    #pragma unroll
    for (int step = 0; step < 2; ++step) {
      short8 af[4], bf[NJ];
      #pragma unroll
      for (int i = 0; i < 4; ++i)
        af[i] = *(const short8*)&lA[buf][wm + i * 16 + ln][((step * 4 + quad) ^ (ln & 7)) * 8];
      #pragma unroll
      for (int j = 0; j < NJ; ++j)
        bf[j] = *(const short8*)&lB[buf][wn + j * 16 + ln][((step * 4 + quad) ^ (ln & 7)) * 8];
      #pragma unroll
      for (int i = 0; i < 4; ++i)
        #pragma unroll
        for (int j = 0; j < NJ; ++j)
          acc[i][j] = __builtin_amdgcn_mfma_f32_16x16x32_bf16(af[i], bf[j], acc[i][j], 0, 0, 0);
    }
  }
  // Epilogue. C/D layout: row = quad*4 + reg, col = lane&15 (m89/m91-verified).
  #pragma unroll
  for (int i = 0; i < 4; ++i)
    #pragma unroll
    for (int j = 0; j < NJ; ++j)
      #pragma unroll
      for (int r = 0; r < 4; ++r) {
        const int row = m0 + wm + i * 16 + quad * 4 + r;
        const int col = n0 + wn + j * 16 + ln;
        if constexpr (__is_same(OutT, float))
          C[(size_t)row * N + col] = acc[i][j][r];
        else
          C[(size_t)row * N + col] = __float2bfloat16(acc[i][j][r]);
      }
}

// ---------------------------------------------------------------------------
// Fused QKV prep (table-driven): rope(Q,K) reshape + V transpose, one qkv
// pass, zero transcendentals. Q scaled by (1/8)*log2(e) (exp2-domain scores).
// ---------------------------------------------------------------------------
__global__ __launch_bounds__(256) void qkv_prep(
    const __hip_bfloat16* __restrict__ qkv,
    const float2* __restrict__ tab,
    __hip_bfloat16* __restrict__ Q,
    __hip_bfloat16* __restrict__ K,
    __hip_bfloat16* __restrict__ Vt) {
  __shared__ __hip_bfloat16 tile[64][65];
  const int s0 = blockIdx.x * 64;
  const int bh = blockIdx.y;
  const int h = bh & 15, b = bh >> 4;
  const int t = threadIdx.x;

  const int pr = t & 31, sl = t >> 5;
  const int d0 = pr * 2;
  const float qs = 0.125f * 1.44269504088896340736f;  // (1/8)*log2(e)
  #pragma unroll
  for (int ss = sl; ss < 64; ss += 8) {
    const int s = s0 + ss;
    const float2 cssn = tab[(size_t)s * 32 + pr];
    const float cs = cssn.x, sn = cssn.y;
    const size_t in_base = (size_t)(b * 2048 + s) * 3072;
    const size_t o = ((size_t)bh * 2048 + s) * 64 + d0;

    __hip_bfloat162 q2 = *(const __hip_bfloat162*)&qkv[in_base + h * 64 + d0];
    float x1 = __bfloat162float(q2.x), x2 = __bfloat162float(q2.y);
    __hip_bfloat162 qo;
    qo.x = __float2bfloat16((x1 * cs - x2 * sn) * qs);
    qo.y = __float2bfloat16((x1 * sn + x2 * cs) * qs);
    *(__hip_bfloat162*)&Q[o] = qo;

    __hip_bfloat162 k2 = *(const __hip_bfloat162*)&qkv[in_base + 1024 + h * 64 + d0];
    x1 = __bfloat162float(k2.x); x2 = __bfloat162float(k2.y);
    __hip_bfloat162 ko;
    ko.x = __float2bfloat16(x1 * cs - x2 * sn);
    ko.y = __float2bfloat16(x1 * sn + x2 * cs);
    *(__hip_bfloat162*)&K[o] = ko;
  }

  const int tx = t & 63, ty = t >> 6;  // ty 0..3
  #pragma unroll
  for (int i = ty; i < 64; i += 4)
    tile[i][tx] = qkv[(size_t)(b * 2048 + s0 + i) * 3072 + 2048 + h * 64 + tx];
  __syncthreads();
  #pragma unroll
  for (int i = ty; i < 64; i += 4)
    Vt[((size_t)bh * 64 + i) * 2048 + s0 + tx] = tile[tx][i];
}

// ---------------------------------------------------------------------------
// Flash-style causal attention — FROZEN at the r7/r11 form (~47 µs floor:
// DS-count r9, LDS-BW r10, TLP r11 all falsified; floor is the per-iter
// VALU chain of 16 quarter-rate v_exp_f32 + cvt, invariant across layouts).
// ---------------------------------------------------------------------------
__global__ __launch_bounds__(256) void attention(
    const __hip_bfloat16* __restrict__ Q,
    const __hip_bfloat16* __restrict__ K,
    const __hip_bfloat16* __restrict__ Vt,
    __hip_bfloat16* __restrict__ attn) {
  __shared__ __hip_bfloat16 lK[2][64][64];    // [buf][sk][d]   XOR-swizzled
  __shared__ __hip_bfloat16 lV[2][64][64];    // [buf][d][sk]   XOR-swizzled
  __shared__ __hip_bfloat16 lP[4][16][72];    // per-wave [q][sk]
  const int t = threadIdx.x;
  const int lane = t & 63, w = t >> 6;
  const int quad = lane >> 4, ln = lane & 15;
  const int id = blockIdx.x;
  const int bh = id & 31;                     // fast index -> XCD spread
  const int qt = 31 - (id >> 5);              // longest q-tiles first
  const int q0 = qt * 64;
  const size_t base = (size_t)bh * 2048 * 64;
  const __hip_bfloat16* Qb = Q + base;
  const __hip_bfloat16* Kb = K + base;
  const __hip_bfloat16* Vb = Vt + base;
  const int b = bh >> 4, h = bh & 15;

  short8 ones;
  #pragma unroll
  for (int i = 0; i < 8; ++i) ones[i] = (short)0x3F80;   // bf16 1.0

  const int srow = lane >> 3;                    // 0..7
  const int schunk = ((lane & 7) ^ srow) * 8;    // swizzled elem offset
  const int rb0 = w * 16;                        // this wave's staging rows

  #pragma unroll
  for (int g = 0; g < 2; ++g) {
    const int rbase = rb0 + g * 8;
    __builtin_amdgcn_global_load_lds(
        (const __attribute__((address_space(1))) void*)
            (Kb + (size_t)(rbase + srow) * 64 + schunk),
        (__attribute__((address_space(3))) void*)&lK[0][rbase][0], 16, 0, 0);
    __builtin_amdgcn_global_load_lds(
        (const __attribute__((address_space(1))) void*)
            (Vb + (size_t)(rbase + srow) * 2048 + schunk),
        (__attribute__((address_space(3))) void*)&lV[0][rbase][0], 16, 0, 0);
  }

  short8 qf[2];
  {
    const size_t qrow = (size_t)(q0 + w * 16 + ln) * 64;
    qf[0] = *(const short8*)(Qb + qrow + quad * 8);
    qf[1] = *(const short8*)(Qb + qrow + 32 + quad * 8);
  }

  float4v acc_o[4];
  #pragma unroll
  for (int dt = 0; dt < 4; ++dt) acc_o[dt] = (float4v){0.f, 0.f, 0.f, 0.f};
  float4v acc_l = (float4v){0.f, 0.f, 0.f, 0.f};

  for (int kt = 0; kt <= qt; ++kt) {
    const int buf = kt & 1;
    __syncthreads();   // drains DMA(kt); frees buf^1

    if (kt < qt) {     // prefetch kt+1 into the other buffer — after barrier
      #pragma unroll
      for (int g = 0; g < 2; ++g) {
        const int rbase = rb0 + g * 8;
        __builtin_amdgcn_global_load_lds(
            (const __attribute__((address_space(1))) void*)
                (Kb + (size_t)((kt + 1) * 64 + rbase + srow) * 64 + schunk),
            (__attribute__((address_space(3))) void*)&lK[buf ^ 1][rbase][0], 16, 0, 0);
        __builtin_amdgcn_global_load_lds(
            (const __attribute__((address_space(1))) void*)
                (Vb + (size_t)(rbase + srow) * 2048 + (kt + 1) * 64 + schunk),
            (__attribute__((address_space(3))) void*)&lV[buf ^ 1][rbase][0], 16, 0, 0);
      }
    }

    float4v s4[4];
    #pragma unroll
    for (int nt = 0; nt < 4; ++nt) {
      float4v a = (float4v){0.f, 0.f, 0.f, 0.f};
      #pragma unroll
      for (int step = 0; step < 2; ++step) {
        short8 kf = *(const short8*)&lK[buf][nt * 16 + ln][((step * 4 + quad) ^ (ln & 7)) * 8];
        a = __builtin_amdgcn_mfma_f32_16x16x32_bf16(qf[step], kf, a, 0, 0, 0);
      }
      s4[nt] = a;
    }
    if (kt == qt) {  // diagonal tile: causal mask (exp2(-64) ~ 5e-20 -> 0)
      #pragma unroll
      for (int nt = 0; nt < 4; ++nt)
        #pragma unroll
        for (int r = 0; r < 4; ++r) {
          const int sk = kt * 64 + nt * 16 + ln;
          const int qr = q0 + w * 16 + quad * 4 + r;
          if (sk > qr) s4[nt][r] = -64.f;
        }
    }
    #pragma unroll
    for (int nt = 0; nt < 4; ++nt)
      #pragma unroll
      for (int r = 0; r < 4; ++r)
        lP[w][quad * 4 + r][nt * 16 + ln] = __float2bfloat16(exp2f(s4[nt][r]));
    #pragma unroll
    for (int step = 0; step < 2; ++step) {
      short8 pf = *(const short8*)&lP[w][ln][step * 32 + quad * 8];
      acc_l = __builtin_amdgcn_mfma_f32_16x16x32_bf16(pf, ones, acc_l, 0, 0, 0);
      #pragma unroll
      for (int dt = 0; dt < 4; ++dt) {
        short8 vf = *(const short8*)&lV[buf][dt * 16 + ln][((step * 4 + quad) ^ (ln & 7)) * 8];
        acc_o[dt] = __builtin_amdgcn_mfma_f32_16x16x32_bf16(pf, vf, acc_o[dt], 0, 0, 0);
      }
    }
  }

  float inv_l[4];
  #pragma unroll
  for (int r = 0; r < 4; ++r) inv_l[r] = 1.0f / acc_l[r];
  #pragma unroll
  for (int dt = 0; dt < 4; ++dt)
    #pragma unroll
    for (int r = 0; r < 4; ++r) {
      const int qr = q0 + w * 16 + quad * 4 + r;
      const size_t rg = (size_t)(b * 2048 + qr);
      const int col = h * 64 + dt * 16 + ln;
      attn[rg * 1024 + col] = __float2bfloat16(acc_o[dt][r] * inv_l[r]);
    }
}

// ---------------------------------------------------------------------------
extern "C" void kernel_launch(void* const* d_in, const int* in_sizes, int n_in,
                              void* d_out, int out_size, void* d_ws, size_t ws_size,
                              hipStream_t stream) {
  const float* x    = (const float*)d_in[0];  // (2,2048,1024) fp32
  const float* Wqkv = (const float*)d_in[1];  // (1024,3072)   fp32
  const float* Wout = (const float*)d_in[2];  // (1024,1024)   fp32
  float* out = (float*)d_out;                 // (2,2048,1024) fp32

  __hip_bfloat16* ws = (__hip_bfloat16*)d_ws;
  __hip_bfloat16* xb    = ws;                          // 4096*1024
  __hip_bfloat16* WqkvT = xb    + (size_t)4096 * 1024; // 3072*1024
  __hip_bfloat16* WoutT = WqkvT + (size_t)3072 * 1024; // 1024*1024
  __hip_bfloat16* qkv   = WoutT + (size_t)1024 * 1024; // 4096*3072
  __hip_bfloat16* Q     = qkv   + (size_t)4096 * 3072; // 32*2048*64
  __hip_bfloat16* K     = Q     + (size_t)32 * 2048 * 64;
  __hip_bfloat16* Vt    = K     + (size_t)32 * 2048 * 64;
  __hip_bfloat16* attn  = Vt    + (size_t)32 * 2048 * 64;  // dedicated
  float2*         tab   = (float2*)(attn + (size_t)4096 * 1024);  // 2048x32

  cvt_and_table<<<4096 + 256, 256, 0, stream>>>(x, xb, tab);
  prep_weights<<<dim3(96, 32, 2), 256, 0, stream>>>(Wqkv, Wout, WqkvT, WoutT);
  gemm_bt<__hip_bfloat16, 128><<<dim3(3072 / 128, 4096 / 128), 256, 0, stream>>>(xb, WqkvT, qkv, 4096, 3072, 1024);
  qkv_prep<<<dim3(32, 32), 256, 0, stream>>>(qkv, tab, Q, K, Vt);
  attention<<<1024, 256, 0, stream>>>(Q, K, Vt, attn);
  gemm_bt<float, 64><<<dim3(1024 / 64, 4096 / 128), 256, 0, stream>>>(attn, WoutT, out, 4096, 1024, 1024);
}

// Round 14
// 189.843 us; speedup vs baseline: 1.0020x; 1.0020x over previous
//
#include <hip/hip_runtime.h>
#include <hip/hip_bf16.h>

typedef __attribute__((ext_vector_type(8))) short short8;     // 8 bf16 (MFMA A/B frag, K=32)
typedef __attribute__((ext_vector_type(4))) float float4v;    // MFMA C/D frag

// ---------------------------------------------------------------------------
// Fused: fp32->bf16 convert of x (blocks 0..4095) + RoPE table (blocks 4096+).
// tab[s][p] = (cos,sin)(s * 10000^(-2p/64)) for s<2048, p<32 — 512 KB,
// L2-resident; consumed by gemm_qkv's fused RoPE epilogue.
// ---------------------------------------------------------------------------
__global__ __launch_bounds__(256) void cvt_and_table(
    const float* __restrict__ in, __hip_bfloat16* __restrict__ out,
    float2* __restrict__ tab) {
  if (blockIdx.x >= 4096) {
    const int i = (blockIdx.x - 4096) * 256 + threadIdx.x;   // 65536
    const int s = i >> 5, p = i & 31;
    const float freq = powf(10000.f, -(float)(p * 2) / 64.f);
    float sn, cs;
    sincosf((float)s * freq, &sn, &cs);
    tab[i] = make_float2(cs, sn);
    return;
  }
  const int i = blockIdx.x * 256 + threadIdx.x;
  const float4 v = *(const float4*)(in + (size_t)i * 4);
  __hip_bfloat16 o[4];
  o[0] = __float2bfloat16(v.x); o[1] = __float2bfloat16(v.y);
  o[2] = __float2bfloat16(v.z); o[3] = __float2bfloat16(v.w);
  *(uint2*)(out + (size_t)i * 4) = *(const uint2*)o;
}

// ---------------------------------------------------------------------------
// Fused weight transposes: z=0 -> WqkvT (1024x3072 -> 3072x1024),
// z=1 -> WoutT (1024x1024 -> 1024x1024). fp32 in, bf16 out.
// ---------------------------------------------------------------------------
__global__ __launch_bounds__(256) void prep_weights(
    const float* __restrict__ Wqkv, const float* __restrict__ Wout,
    __hip_bfloat16* __restrict__ WqkvT, __hip_bfloat16* __restrict__ WoutT) {
  const int z = blockIdx.z;
  if (z == 1 && blockIdx.x >= 32) return;
  const float* in = z ? Wout : Wqkv;
  __hip_bfloat16* out = z ? WoutT : WqkvT;
  const int R = 1024, C = z ? 1024 : 3072;
  __shared__ __hip_bfloat16 tile[32][33];
  const int c0 = blockIdx.x * 32, r0 = blockIdx.y * 32;
  const int tx = threadIdx.x & 31, ty = threadIdx.x >> 5;  // ty 0..7
  #pragma unroll
  for (int i = ty; i < 32; i += 8)
    tile[i][tx] = __float2bfloat16(in[(size_t)(r0 + i) * C + (c0 + tx)]);
  __syncthreads();
  #pragma unroll
  for (int i = ty; i < 32; i += 8)
    out[(size_t)(c0 + i) * R + (r0 + tx)] = tile[tx][i];
}

// ---------------------------------------------------------------------------
// gemm_qkv: x (4096x1024 bf16) @ WqkvT^T with FUSED RoPE/reshape epilogue.
// Single-buffer r6/r12 K-loop (dbuf regressed in r13: LDS 36->64 KB cost
// 4->2 blocks/CU — occupancy beat barrier-drain savings; lesson kept).
// n-tile (128 wide) lies entirely in one third: 0..7 -> Q, 8..15 -> K,
// 16..23 -> V (1024 % 128 == 0), so the epilogue branch is block-uniform.
//   Q/K: RoPE pair = adjacent columns = adjacent lanes -> __shfl_xor(own,1);
//        both lanes share pr = d>>1 -> same (cos,sin) from tab. Q also gets
//        qs = (1/8)*log2(e) (exp2-domain scores).
//   V:   lane holds 4 consecutive s for fixed d -> 8B store into Vt[d][s].
// Eliminates the qkv intermediate (24 MB write + 25 MB read) and qkv_prep.
// ---------------------------------------------------------------------------
__global__ __launch_bounds__(256) void gemm_qkv(
    const __hip_bfloat16* __restrict__ A,    // x bf16 (4096 x 1024)
    const __hip_bfloat16* __restrict__ Bt,   // WqkvT (3072 x 1024)
    const float2* __restrict__ tab,
    __hip_bfloat16* __restrict__ Q,
    __hip_bfloat16* __restrict__ K,
    __hip_bfloat16* __restrict__ Vt) {
  const int KK = 1024;
  __shared__ __hip_bfloat16 lA[128][64];
  __shared__ __hip_bfloat16 lB[128][64];
  const int t = threadIdx.x;
  const int lane = t & 63, wave = t >> 6;
  const int quad = lane >> 4, ln = lane & 15;
  const int m0 = blockIdx.y * 128, n0 = blockIdx.x * 128;
  const int wm = (wave >> 1) * 64, wn = (wave & 1) * 64;
  const int srow = lane >> 3;                    // 0..7
  const int schunk = ((lane & 7) ^ srow) * 8;    // swizzled elem offset

  float4v acc[4][4];
  #pragma unroll
  for (int i = 0; i < 4; ++i)
    #pragma unroll
    for (int j = 0; j < 4; ++j)
      acc[i][j] = (float4v){0.f, 0.f, 0.f, 0.f};

  for (int kt = 0; kt < KK; kt += 64) {
    __syncthreads();
    #pragma unroll
    for (int q = 0; q < 4; ++q) {
      const int rbase = wave * 32 + q * 8;
      __builtin_amdgcn_global_load_lds(
          (const __attribute__((address_space(1))) void*)
              (A + (size_t)(m0 + rbase + srow) * KK + kt + schunk),
          (__attribute__((address_space(3))) void*)&lA[rbase][0], 16, 0, 0);
      __builtin_amdgcn_global_load_lds(
          (const __attribute__((address_space(1))) void*)
              (Bt + (size_t)(n0 + rbase + srow) * KK + kt + schunk),
          (__attribute__((address_space(3))) void*)&lB[rbase][0], 16, 0, 0);
    }
    __syncthreads();
    #pragma unroll
    for (int step = 0; step < 2; ++step) {
      short8 af[4], bf[4];
      #pragma unroll
      for (int i = 0; i < 4; ++i)
        af[i] = *(const short8*)&lA[wm + i * 16 + ln][((step * 4 + quad) ^ (ln & 7)) * 8];
      #pragma unroll
      for (int j = 0; j < 4; ++j)
        bf[j] = *(const short8*)&lB[wn + j * 16 + ln][((step * 4 + quad) ^ (ln & 7)) * 8];
      #pragma unroll
      for (int i = 0; i < 4; ++i)
        #pragma unroll
        for (int j = 0; j < 4; ++j)
          acc[i][j] = __builtin_amdgcn_mfma_f32_16x16x32_bf16(af[i], bf[j], acc[i][j], 0, 0, 0);
    }
  }

  // ---- fused epilogue: C-layout row = quad*4+reg, col = lane&15 ----
  const int third = n0 >> 10;              // 0=Q, 1=K, 2=V (block-uniform)
  const int cbase = (n0 & 1023) + wn;
  const float qs = 0.125f * 1.44269504088896340736f;

  if (third == 2) {
    // V: Vt[(b*16+h)*64 + d][s], 4 consecutive s per frag -> uint2 store
    #pragma unroll
    for (int i = 0; i < 4; ++i)
      #pragma unroll
      for (int j = 0; j < 4; ++j) {
        const int c = cbase + j * 16 + ln;
        const int h = c >> 6, d = c & 63;
        const int row0 = m0 + wm + i * 16 + quad * 4;
        const int b = row0 >> 11, s = row0 & 2047;
        __hip_bfloat16 o4[4];
        #pragma unroll
        for (int r = 0; r < 4; ++r) o4[r] = __float2bfloat16(acc[i][j][r]);
        *(uint2*)&Vt[((size_t)(b * 16 + h) * 64 + d) * 2048 + s] = *(const uint2*)o4;
      }
  } else {
    __hip_bfloat16* O = (third == 0) ? Q : K;
    #pragma unroll
    for (int i = 0; i < 4; ++i)
      #pragma unroll
      for (int j = 0; j < 4; ++j) {
        const int c = cbase + j * 16 + ln;
        const int h = c >> 6, d = c & 63, pr = d >> 1;
        #pragma unroll
        for (int r = 0; r < 4; ++r) {
          const int row = m0 + wm + i * 16 + quad * 4 + r;
          const int b = row >> 11, s = row & 2047;
          const float2 t2 = tab[(size_t)s * 32 + pr];
          const float own = acc[i][j][r];
          const float oth = __shfl_xor(own, 1);
          float v = (lane & 1) ? (oth * t2.y + own * t2.x)    // odd col: x1*sn + x2*cs
                               : (own * t2.x - oth * t2.y);   // even col: x1*cs - x2*sn
          if (third == 0) v *= qs;
          O[((size_t)(b * 16 + h) * 2048 + s) * 64 + d] = __float2bfloat16(v);
        }
      }
  }
}

// ---------------------------------------------------------------------------
// gemm_bt (r12 single-buffer form, reverted from r13's dbuf regression):
// 128xBN tile, BK=64, global_load_lds width=16, stride-64 LDS + XOR swizzle.
// ---------------------------------------------------------------------------
template <typename OutT, int BN>
__global__ __launch_bounds__(256) void gemm_bt(
    const __hip_bfloat16* __restrict__ A,
    const __hip_bfloat16* __restrict__ Bt,
    OutT* __restrict__ C,
    int M, int N, int K) {
  __shared__ __hip_bfloat16 lA[128][64];
  __shared__ __hip_bfloat16 lB[BN][64];
  constexpr int NJ = BN / 32;
  const int t = threadIdx.x;
  const int lane = t & 63, wave = t >> 6;
  const int quad = lane >> 4, ln = lane & 15;
  const int m0 = blockIdx.y * 128, n0 = blockIdx.x * BN;
  const int wm = (wave >> 1) * 64, wn = (wave & 1) * (BN / 2);
  const int srow = lane >> 3;
  const int schunk = ((lane & 7) ^ srow) * 8;

  float4v acc[4][NJ];
  #pragma unroll
  for (int i = 0; i < 4; ++i)
    #pragma unroll
    for (int j = 0; j < NJ; ++j)
      acc[i][j] = (float4v){0.f, 0.f, 0.f, 0.f};

  for (int kt = 0; kt < K; kt += 64) {
    __syncthreads();
    #pragma unroll
    for (int q = 0; q < 4; ++q) {
      const int rbase = wave * 32 + q * 8;
      __builtin_amdgcn_global_load_lds(
          (const __attribute__((address_space(1))) void*)
              (A + (size_t)(m0 + rbase + srow) * K + kt + schunk),
          (__attribute__((address_space(3))) void*)&lA[rbase][0], 16, 0, 0);
    }
    #pragma unroll
    for (int g = 0; g < BN / 32; ++g) {
      const int rbase = wave * (BN / 4) + g * 8;
      __builtin_amdgcn_global_load_lds(
          (const __attribute__((address_space(1))) void*)
              (Bt + (size_t)(n0 + rbase + srow) * K + kt + schunk),
          (__attribute__((address_space(3))) void*)&lB[rbase][0], 16, 0, 0);
    }
    __syncthreads();
    #pragma unroll
    for (int step = 0; step < 2; ++step) {
      short8 af[4], bf[NJ];
      #pragma unroll
      for (int i = 0; i < 4; ++i)
        af[i] = *(const short8*)&lA[wm + i * 16 + ln][((step * 4 + quad) ^ (ln & 7)) * 8];
      #pragma unroll
      for (int j = 0; j < NJ; ++j)
        bf[j] = *(const short8*)&lB[wn + j * 16 + ln][((step * 4 + quad) ^ (ln & 7)) * 8];
      #pragma unroll
      for (int i = 0; i < 4; ++i)
        #pragma unroll
        for (int j = 0; j < NJ; ++j)
          acc[i][j] = __builtin_amdgcn_mfma_f32_16x16x32_bf16(af[i], bf[j], acc[i][j], 0, 0, 0);
    }
  }
  #pragma unroll
  for (int i = 0; i < 4; ++i)
    #pragma unroll
    for (int j = 0; j < NJ; ++j)
      #pragma unroll
      for (int r = 0; r < 4; ++r) {
        const int row = m0 + wm + i * 16 + quad * 4 + r;
        const int col = n0 + wn + j * 16 + ln;
        if constexpr (__is_same(OutT, float))
          C[(size_t)row * N + col] = acc[i][j][r];
        else
          C[(size_t)row * N + col] = __float2bfloat16(acc[i][j][r]);
      }
}

// ---------------------------------------------------------------------------
// Flash-style causal attention — FROZEN at the r7/r11 form (~47 µs floor:
// DS-count r9, LDS-BW r10, TLP r11 all falsified; floor is the per-iter
// VALU chain of 16 quarter-rate v_exp_f32 + cvt, invariant across layouts).
// ---------------------------------------------------------------------------
__global__ __launch_bounds__(256) void attention(
    const __hip_bfloat16* __restrict__ Q,
    const __hip_bfloat16* __restrict__ K,
    const __hip_bfloat16* __restrict__ Vt,
    __hip_bfloat16* __restrict__ attn) {
  __shared__ __hip_bfloat16 lK[2][64][64];    // [buf][sk][d]   XOR-swizzled
  __shared__ __hip_bfloat16 lV[2][64][64];    // [buf][d][sk]   XOR-swizzled
  __shared__ __hip_bfloat16 lP[4][16][72];    // per-wave [q][sk]
  const int t = threadIdx.x;
  const int lane = t & 63, w = t >> 6;
  const int quad = lane >> 4, ln = lane & 15;
  const int id = blockIdx.x;
  const int bh = id & 31;                     // fast index -> XCD spread
  const int qt = 31 - (id >> 5);              // longest q-tiles first
  const int q0 = qt * 64;
  const size_t base = (size_t)bh * 2048 * 64;
  const __hip_bfloat16* Qb = Q + base;
  const __hip_bfloat16* Kb = K + base;
  const __hip_bfloat16* Vb = Vt + base;
  const int b = bh >> 4, h = bh & 15;

  short8 ones;
  #pragma unroll
  for (int i = 0; i < 8; ++i) ones[i] = (short)0x3F80;   // bf16 1.0

  const int srow = lane >> 3;
  const int schunk = ((lane & 7) ^ srow) * 8;
  const int rb0 = w * 16;

  #pragma unroll
  for (int g = 0; g < 2; ++g) {
    const int rbase = rb0 + g * 8;
    __builtin_amdgcn_global_load_lds(
        (const __attribute__((address_space(1))) void*)
            (Kb + (size_t)(rbase + srow) * 64 + schunk),
        (__attribute__((address_space(3))) void*)&lK[0][rbase][0], 16, 0, 0);
    __builtin_amdgcn_global_load_lds(
        (const __attribute__((address_space(1))) void*)
            (Vb + (size_t)(rbase + srow) * 2048 + schunk),
        (__attribute__((address_space(3))) void*)&lV[0][rbase][0], 16, 0, 0);
  }

  short8 qf[2];
  {
    const size_t qrow = (size_t)(q0 + w * 16 + ln) * 64;
    qf[0] = *(const short8*)(Qb + qrow + quad * 8);
    qf[1] = *(const short8*)(Qb + qrow + 32 + quad * 8);
  }

  float4v acc_o[4];
  #pragma unroll
  for (int dt = 0; dt < 4; ++dt) acc_o[dt] = (float4v){0.f, 0.f, 0.f, 0.f};
  float4v acc_l = (float4v){0.f, 0.f, 0.f, 0.f};

  for (int kt = 0; kt <= qt; ++kt) {
    const int buf = kt & 1;
    __syncthreads();

    if (kt < qt) {
      #pragma unroll
      for (int g = 0; g < 2; ++g) {
        const int rbase = rb0 + g * 8;
        __builtin_amdgcn_global_load_lds(
            (const __attribute__((address_space(1))) void*)
                (Kb + (size_t)((kt + 1) * 64 + rbase + srow) * 64 + schunk),
            (__attribute__((address_space(3))) void*)&lK[buf ^ 1][rbase][0], 16, 0, 0);
        __builtin_amdgcn_global_load_lds(
            (const __attribute__((address_space(1))) void*)
                (Vb + (size_t)(rbase + srow) * 2048 + (kt + 1) * 64 + schunk),
            (__attribute__((address_space(3))) void*)&lV[buf ^ 1][rbase][0], 16, 0, 0);
      }
    }

    float4v s4[4];
    #pragma unroll
    for (int nt = 0; nt < 4; ++nt) {
      float4v a = (float4v){0.f, 0.f, 0.f, 0.f};
      #pragma unroll
      for (int step = 0; step < 2; ++step) {
        short8 kf = *(const short8*)&lK[buf][nt * 16 + ln][((step * 4 + quad) ^ (ln & 7)) * 8];
        a = __builtin_amdgcn_mfma_f32_16x16x32_bf16(qf[step], kf, a, 0, 0, 0);
      }
      s4[nt] = a;
    }
    if (kt == qt) {
      #pragma unroll
      for (int nt = 0; nt < 4; ++nt)
        #pragma unroll
        for (int r = 0; r < 4; ++r) {
          const int sk = kt * 64 + nt * 16 + ln;
          const int qr = q0 + w * 16 + quad * 4 + r;
          if (sk > qr) s4[nt][r] = -64.f;
        }
    }
    #pragma unroll
    for (int nt = 0; nt < 4; ++nt)
      #pragma unroll
      for (int r = 0; r < 4; ++r)
        lP[w][quad * 4 + r][nt * 16 + ln] = __float2bfloat16(exp2f(s4[nt][r]));
    #pragma unroll
    for (int step = 0; step < 2; ++step) {
      short8 pf = *(const short8*)&lP[w][ln][step * 32 + quad * 8];
      acc_l = __builtin_amdgcn_mfma_f32_16x16x32_bf16(pf, ones, acc_l, 0, 0, 0);
      #pragma unroll
      for (int dt = 0; dt < 4; ++dt) {
        short8 vf = *(const short8*)&lV[buf][dt * 16 + ln][((step * 4 + quad) ^ (ln & 7)) * 8];
        acc_o[dt] = __builtin_amdgcn_mfma_f32_16x16x32_bf16(pf, vf, acc_o[dt], 0, 0, 0);
      }
    }
  }

  float inv_l[4];
  #pragma unroll
  for (int r = 0; r < 4; ++r) inv_l[r] = 1.0f / acc_l[r];
  #pragma unroll
  for (int dt = 0; dt < 4; ++dt)
    #pragma unroll
    for (int r = 0; r < 4; ++r) {
      const int qr = q0 + w * 16 + quad * 4 + r;
      const size_t rg = (size_t)(b * 2048 + qr);
      const int col = h * 64 + dt * 16 + ln;
      attn[rg * 1024 + col] = __float2bfloat16(acc_o[dt][r] * inv_l[r]);
    }
}

// ---------------------------------------------------------------------------
extern "C" void kernel_launch(void* const* d_in, const int* in_sizes, int n_in,
                              void* d_out, int out_size, void* d_ws, size_t ws_size,
                              hipStream_t stream) {
  const float* x    = (const float*)d_in[0];  // (2,2048,1024) fp32
  const float* Wqkv = (const float*)d_in[1];  // (1024,3072)   fp32
  const float* Wout = (const float*)d_in[2];  // (1024,1024)   fp32
  float* out = (float*)d_out;                 // (2,2048,1024) fp32

  __hip_bfloat16* ws = (__hip_bfloat16*)d_ws;
  __hip_bfloat16* xb    = ws;                          // 4096*1024
  __hip_bfloat16* WqkvT = xb    + (size_t)4096 * 1024; // 3072*1024
  __hip_bfloat16* WoutT = WqkvT + (size_t)3072 * 1024; // 1024*1024
  __hip_bfloat16* Q     = WoutT + (size_t)1024 * 1024; // 32*2048*64
  __hip_bfloat16* K     = Q     + (size_t)32 * 2048 * 64;
  __hip_bfloat16* Vt    = K     + (size_t)32 * 2048 * 64;
  __hip_bfloat16* attn  = Vt    + (size_t)32 * 2048 * 64;  // dedicated
  float2*         tab   = (float2*)(attn + (size_t)4096 * 1024);  // 2048x32

  cvt_and_table<<<4096 + 256, 256, 0, stream>>>(x, xb, tab);
  prep_weights<<<dim3(96, 32, 2), 256, 0, stream>>>(Wqkv, Wout, WqkvT, WoutT);
  gemm_qkv<<<dim3(24, 32), 256, 0, stream>>>(xb, WqkvT, tab, Q, K, Vt);
  attention<<<1024, 256, 0, stream>>>(Q, K, Vt, attn);
  gemm_bt<float, 64><<<dim3(1024 / 64, 4096 / 128), 256, 0, stream>>>(attn, WoutT, out, 4096, 1024, 1024);
}

// Round 15
// 185.571 us; speedup vs baseline: 1.0250x; 1.0230x over previous
//
#include <hip/hip_runtime.h>
#include <hip/hip_bf16.h>

typedef __attribute__((ext_vector_type(8))) short short8;     // 8 bf16 (MFMA A/B frag, K=32)
typedef __attribute__((ext_vector_type(4))) float float4v;    // MFMA C/D frag

// ---------------------------------------------------------------------------
// Fused: fp32->bf16 convert of x (blocks 0..4095) + RoPE table (blocks 4096+).
// tab[s][p] = (cos,sin)(s * 10000^(-2p/64)) for s<2048, p<32 — 512 KB,
// L2-resident for qkv_prep.
// ---------------------------------------------------------------------------
__global__ __launch_bounds__(256) void cvt_and_table(
    const float* __restrict__ in, __hip_bfloat16* __restrict__ out,
    float2* __restrict__ tab) {
  if (blockIdx.x >= 4096) {
    const int i = (blockIdx.x - 4096) * 256 + threadIdx.x;   // 65536
    const int s = i >> 5, p = i & 31;
    const float freq = powf(10000.f, -(float)(p * 2) / 64.f);
    float sn, cs;
    sincosf((float)s * freq, &sn, &cs);
    tab[i] = make_float2(cs, sn);
    return;
  }
  const int i = blockIdx.x * 256 + threadIdx.x;
  const float4 v = *(const float4*)(in + (size_t)i * 4);
  __hip_bfloat16 o[4];
  o[0] = __float2bfloat16(v.x); o[1] = __float2bfloat16(v.y);
  o[2] = __float2bfloat16(v.z); o[3] = __float2bfloat16(v.w);
  *(uint2*)(out + (size_t)i * 4) = *(const uint2*)o;
}

// ---------------------------------------------------------------------------
// Fused weight transposes: z=0 -> WqkvT, z=1 -> WoutT. fp32 in, bf16 out.
// ---------------------------------------------------------------------------
__global__ __launch_bounds__(256) void prep_weights(
    const float* __restrict__ Wqkv, const float* __restrict__ Wout,
    __hip_bfloat16* __restrict__ WqkvT, __hip_bfloat16* __restrict__ WoutT) {
  const int z = blockIdx.z;
  if (z == 1 && blockIdx.x >= 32) return;
  const float* in = z ? Wout : Wqkv;
  __hip_bfloat16* out = z ? WoutT : WqkvT;
  const int R = 1024, C = z ? 1024 : 3072;
  __shared__ __hip_bfloat16 tile[32][33];
  const int c0 = blockIdx.x * 32, r0 = blockIdx.y * 32;
  const int tx = threadIdx.x & 31, ty = threadIdx.x >> 5;  // ty 0..7
  #pragma unroll
  for (int i = ty; i < 32; i += 8)
    tile[i][tx] = __float2bfloat16(in[(size_t)(r0 + i) * C + (c0 + tx)]);
  __syncthreads();
  #pragma unroll
  for (int i = ty; i < 32; i += 8)
    out[(size_t)(c0 + i) * R + (r0 + tx)] = tile[tx][i];
}

// ---------------------------------------------------------------------------
// gemm_bt: C (MxN, OutT) = A (MxK, row-major bf16) @ Bt^T  (Bt is NxK bf16)
// BMxBN tile, BK=64, 256 threads = 4 waves. Single-buffer r6/r12 K-loop
// (dbuf regressed in r13: occupancy loss beat drain savings).
// global_load_lds width=16 staging, stride-64 LDS + XOR chunk swizzle.
// BM=BN=64 for gemm2: grid 512->1024 blocks, LDS 16 KB -> 4+ blocks/CU
// (gemm2 at 190 TF was TLP-starved at 2 blocks/CU; smaller tile trades
// MFMA:staging ratio for 2x+ resident waves).
// ---------------------------------------------------------------------------
template <typename OutT, int BM, int BN>
__global__ __launch_bounds__(256) void gemm_bt(
    const __hip_bfloat16* __restrict__ A,
    const __hip_bfloat16* __restrict__ Bt,
    OutT* __restrict__ C,
    int M, int N, int K) {
  __shared__ __hip_bfloat16 lA[BM][64];
  __shared__ __hip_bfloat16 lB[BN][64];
  constexpr int NI = BM / 32, NJ = BN / 32;      // 16-row/col tiles per wave
  const int t = threadIdx.x;
  const int lane = t & 63, wave = t >> 6;
  const int quad = lane >> 4, ln = lane & 15;
  const int m0 = blockIdx.y * BM, n0 = blockIdx.x * BN;
  const int wm = (wave >> 1) * (BM / 2), wn = (wave & 1) * (BN / 2);
  const int srow = lane >> 3;                    // 0..7
  const int schunk = ((lane & 7) ^ srow) * 8;    // swizzled elem offset

  float4v acc[NI][NJ];
  #pragma unroll
  for (int i = 0; i < NI; ++i)
    #pragma unroll
    for (int j = 0; j < NJ; ++j)
      acc[i][j] = (float4v){0.f, 0.f, 0.f, 0.f};

  for (int kt = 0; kt < K; kt += 64) {
    __syncthreads();   // previous iter's frag reads done before DMA overwrite
    #pragma unroll
    for (int g = 0; g < BM / 32; ++g) {
      const int rbase = wave * (BM / 4) + g * 8;
      __builtin_amdgcn_global_load_lds(
          (const __attribute__((address_space(1))) void*)
              (A + (size_t)(m0 + rbase + srow) * K + kt + schunk),
          (__attribute__((address_space(3))) void*)&lA[rbase][0], 16, 0, 0);
    }
    #pragma unroll
    for (int g = 0; g < BN / 32; ++g) {
      const int rbase = wave * (BN / 4) + g * 8;
      __builtin_amdgcn_global_load_lds(
          (const __attribute__((address_space(1))) void*)
              (Bt + (size_t)(n0 + rbase + srow) * K + kt + schunk),
          (__attribute__((address_space(3))) void*)&lB[rbase][0], 16, 0, 0);
    }
    __syncthreads();   // vmcnt(0) drain: DMA complete, LDS visible
    #pragma unroll
    for (int step = 0; step < 2; ++step) {
      short8 af[NI], bf[NJ];
      #pragma unroll
      for (int i = 0; i < NI; ++i)
        af[i] = *(const short8*)&lA[wm + i * 16 + ln][((step * 4 + quad) ^ (ln & 7)) * 8];
      #pragma unroll
      for (int j = 0; j < NJ; ++j)
        bf[j] = *(const short8*)&lB[wn + j * 16 + ln][((step * 4 + quad) ^ (ln & 7)) * 8];
      #pragma unroll
      for (int i = 0; i < NI; ++i)
        #pragma unroll
        for (int j = 0; j < NJ; ++j)
          acc[i][j] = __builtin_amdgcn_mfma_f32_16x16x32_bf16(af[i], bf[j], acc[i][j], 0, 0, 0);
    }
  }
  // Epilogue. C/D layout: row = quad*4 + reg, col = lane&15 (m89/m91-verified).
  #pragma unroll
  for (int i = 0; i < NI; ++i)
    #pragma unroll
    for (int j = 0; j < NJ; ++j)
      #pragma unroll
      for (int r = 0; r < 4; ++r) {
        const int row = m0 + wm + i * 16 + quad * 4 + r;
        const int col = n0 + wn + j * 16 + ln;
        if constexpr (__is_same(OutT, float))
          C[(size_t)row * N + col] = acc[i][j][r];
        else
          C[(size_t)row * N + col] = __float2bfloat16(acc[i][j][r]);
      }
}

// ---------------------------------------------------------------------------
// Fused QKV prep (table-driven, r12 form): rope(Q,K) reshape + V transpose,
// one qkv pass, zero transcendentals. Q scaled by (1/8)*log2(e).
// (r14's gemm-epilogue fusion was a wash: epilogue shfl/table chain cost
// what the saved qkv round-trip bought. Reverted.)
// ---------------------------------------------------------------------------
__global__ __launch_bounds__(256) void qkv_prep(
    const __hip_bfloat16* __restrict__ qkv,
    const float2* __restrict__ tab,
    __hip_bfloat16* __restrict__ Q,
    __hip_bfloat16* __restrict__ K,
    __hip_bfloat16* __restrict__ Vt) {
  __shared__ __hip_bfloat16 tile[64][65];
  const int s0 = blockIdx.x * 64;
  const int bh = blockIdx.y;
  const int h = bh & 15, b = bh >> 4;
  const int t = threadIdx.x;

  const int pr = t & 31, sl = t >> 5;
  const int d0 = pr * 2;
  const float qs = 0.125f * 1.44269504088896340736f;  // (1/8)*log2(e)
  #pragma unroll
  for (int ss = sl; ss < 64; ss += 8) {
    const int s = s0 + ss;
    const float2 cssn = tab[(size_t)s * 32 + pr];
    const float cs = cssn.x, sn = cssn.y;
    const size_t in_base = (size_t)(b * 2048 + s) * 3072;
    const size_t o = ((size_t)bh * 2048 + s) * 64 + d0;

    __hip_bfloat162 q2 = *(const __hip_bfloat162*)&qkv[in_base + h * 64 + d0];
    float x1 = __bfloat162float(q2.x), x2 = __bfloat162float(q2.y);
    __hip_bfloat162 qo;
    qo.x = __float2bfloat16((x1 * cs - x2 * sn) * qs);
    qo.y = __float2bfloat16((x1 * sn + x2 * cs) * qs);
    *(__hip_bfloat162*)&Q[o] = qo;

    __hip_bfloat162 k2 = *(const __hip_bfloat162*)&qkv[in_base + 1024 + h * 64 + d0];
    x1 = __bfloat162float(k2.x); x2 = __bfloat162float(k2.y);
    __hip_bfloat162 ko;
    ko.x = __float2bfloat16(x1 * cs - x2 * sn);
    ko.y = __float2bfloat16(x1 * sn + x2 * cs);
    *(__hip_bfloat162*)&K[o] = ko;
  }

  const int tx = t & 63, ty = t >> 6;  // ty 0..3
  #pragma unroll
  for (int i = ty; i < 64; i += 4)
    tile[i][tx] = qkv[(size_t)(b * 2048 + s0 + i) * 3072 + 2048 + h * 64 + tx];
  __syncthreads();
  #pragma unroll
  for (int i = ty; i < 64; i += 4)
    Vt[((size_t)bh * 64 + i) * 2048 + s0 + tx] = tile[tx][i];
}

// ---------------------------------------------------------------------------
// Flash-style causal attention — FROZEN at the r7/r11 form (~47 µs floor:
// DS-count r9, LDS-BW r10, TLP r11 all falsified; floor is the per-iter
// VALU chain of 16 quarter-rate v_exp_f32 + cvt, invariant across layouts).
// ---------------------------------------------------------------------------
__global__ __launch_bounds__(256) void attention(
    const __hip_bfloat16* __restrict__ Q,
    const __hip_bfloat16* __restrict__ K,
    const __hip_bfloat16* __restrict__ Vt,
    __hip_bfloat16* __restrict__ attn) {
  __shared__ __hip_bfloat16 lK[2][64][64];    // [buf][sk][d]   XOR-swizzled
  __shared__ __hip_bfloat16 lV[2][64][64];    // [buf][d][sk]   XOR-swizzled
  __shared__ __hip_bfloat16 lP[4][16][72];    // per-wave [q][sk]
  const int t = threadIdx.x;
  const int lane = t & 63, w = t >> 6;
  const int quad = lane >> 4, ln = lane & 15;
  const int id = blockIdx.x;
  const int bh = id & 31;                     // fast index -> XCD spread
  const int qt = 31 - (id >> 5);              // longest q-tiles first
  const int q0 = qt * 64;
  const size_t base = (size_t)bh * 2048 * 64;
  const __hip_bfloat16* Qb = Q + base;
  const __hip_bfloat16* Kb = K + base;
  const __hip_bfloat16* Vb = Vt + base;
  const int b = bh >> 4, h = bh & 15;

  short8 ones;
  #pragma unroll
  for (int i = 0; i < 8; ++i) ones[i] = (short)0x3F80;   // bf16 1.0

  const int srow = lane >> 3;
  const int schunk = ((lane & 7) ^ srow) * 8;
  const int rb0 = w * 16;

  #pragma unroll
  for (int g = 0; g < 2; ++g) {
    const int rbase = rb0 + g * 8;
    __builtin_amdgcn_global_load_lds(
        (const __attribute__((address_space(1))) void*)
            (Kb + (size_t)(rbase + srow) * 64 + schunk),
        (__attribute__((address_space(3))) void*)&lK[0][rbase][0], 16, 0, 0);
    __builtin_amdgcn_global_load_lds(
        (const __attribute__((address_space(1))) void*)
            (Vb + (size_t)(rbase + srow) * 2048 + schunk),
        (__attribute__((address_space(3))) void*)&lV[0][rbase][0], 16, 0, 0);
  }

  short8 qf[2];
  {
    const size_t qrow = (size_t)(q0 + w * 16 + ln) * 64;
    qf[0] = *(const short8*)(Qb + qrow + quad * 8);
    qf[1] = *(const short8*)(Qb + qrow + 32 + quad * 8);
  }

  float4v acc_o[4];
  #pragma unroll
  for (int dt = 0; dt < 4; ++dt) acc_o[dt] = (float4v){0.f, 0.f, 0.f, 0.f};
  float4v acc_l = (float4v){0.f, 0.f, 0.f, 0.f};

  for (int kt = 0; kt <= qt; ++kt) {
    const int buf = kt & 1;
    __syncthreads();

    if (kt < qt) {
      #pragma unroll
      for (int g = 0; g < 2; ++g) {
        const int rbase = rb0 + g * 8;
        __builtin_amdgcn_global_load_lds(
            (const __attribute__((address_space(1))) void*)
                (Kb + (size_t)((kt + 1) * 64 + rbase + srow) * 64 + schunk),
            (__attribute__((address_space(3))) void*)&lK[buf ^ 1][rbase][0], 16, 0, 0);
        __builtin_amdgcn_global_load_lds(
            (const __attribute__((address_space(1))) void*)
                (Vb + (size_t)(rbase + srow) * 2048 + (kt + 1) * 64 + schunk),
            (__attribute__((address_space(3))) void*)&lV[buf ^ 1][rbase][0], 16, 0, 0);
      }
    }

    float4v s4[4];
    #pragma unroll
    for (int nt = 0; nt < 4; ++nt) {
      float4v a = (float4v){0.f, 0.f, 0.f, 0.f};
      #pragma unroll
      for (int step = 0; step < 2; ++step) {
        short8 kf = *(const short8*)&lK[buf][nt * 16 + ln][((step * 4 + quad) ^ (ln & 7)) * 8];
        a = __builtin_amdgcn_mfma_f32_16x16x32_bf16(qf[step], kf, a, 0, 0, 0);
      }
      s4[nt] = a;
    }
    if (kt == qt) {
      #pragma unroll
      for (int nt = 0; nt < 4; ++nt)
        #pragma unroll
        for (int r = 0; r < 4; ++r) {
          const int sk = kt * 64 + nt * 16 + ln;
          const int qr = q0 + w * 16 + quad * 4 + r;
          if (sk > qr) s4[nt][r] = -64.f;
        }
    }
    #pragma unroll
    for (int nt = 0; nt < 4; ++nt)
      #pragma unroll
      for (int r = 0; r < 4; ++r)
        lP[w][quad * 4 + r][nt * 16 + ln] = __float2bfloat16(exp2f(s4[nt][r]));
    #pragma unroll
    for (int step = 0; step < 2; ++step) {
      short8 pf = *(const short8*)&lP[w][ln][step * 32 + quad * 8];
      acc_l = __builtin_amdgcn_mfma_f32_16x16x32_bf16(pf, ones, acc_l, 0, 0, 0);
      #pragma unroll
      for (int dt = 0; dt < 4; ++dt) {
        short8 vf = *(const short8*)&lV[buf][dt * 16 + ln][((step * 4 + quad) ^ (ln & 7)) * 8];
        acc_o[dt] = __builtin_amdgcn_mfma_f32_16x16x32_bf16(pf, vf, acc_o[dt], 0, 0, 0);
      }
    }
  }

  float inv_l[4];
  #pragma unroll
  for (int r = 0; r < 4; ++r) inv_l[r] = 1.0f / acc_l[r];
  #pragma unroll
  for (int dt = 0; dt < 4; ++dt)
    #pragma unroll
    for (int r = 0; r < 4; ++r) {
      const int qr = q0 + w * 16 + quad * 4 + r;
      const size_t rg = (size_t)(b * 2048 + qr);
      const int col = h * 64 + dt * 16 + ln;
      attn[rg * 1024 + col] = __float2bfloat16(acc_o[dt][r] * inv_l[r]);
    }
}

// ---------------------------------------------------------------------------
extern "C" void kernel_launch(void* const* d_in, const int* in_sizes, int n_in,
                              void* d_out, int out_size, void* d_ws, size_t ws_size,
                              hipStream_t stream) {
  const float* x    = (const float*)d_in[0];  // (2,2048,1024) fp32
  const float* Wqkv = (const float*)d_in[1];  // (1024,3072)   fp32
  const float* Wout = (const float*)d_in[2];  // (1024,1024)   fp32
  float* out = (float*)d_out;                 // (2,2048,1024) fp32

  __hip_bfloat16* ws = (__hip_bfloat16*)d_ws;
  __hip_bfloat16* xb    = ws;                          // 4096*1024
  __hip_bfloat16* WqkvT = xb    + (size_t)4096 * 1024; // 3072*1024
  __hip_bfloat16* WoutT = WqkvT + (size_t)3072 * 1024; // 1024*1024
  __hip_bfloat16* qkv   = WoutT + (size_t)1024 * 1024; // 4096*3072
  __hip_bfloat16* Q     = qkv   + (size_t)4096 * 3072; // 32*2048*64
  __hip_bfloat16* K     = Q     + (size_t)32 * 2048 * 64;
  __hip_bfloat16* Vt    = K     + (size_t)32 * 2048 * 64;
  __hip_bfloat16* attn  = Vt    + (size_t)32 * 2048 * 64;  // dedicated
  float2*         tab   = (float2*)(attn + (size_t)4096 * 1024);  // 2048x32

  cvt_and_table<<<4096 + 256, 256, 0, stream>>>(x, xb, tab);
  prep_weights<<<dim3(96, 32, 2), 256, 0, stream>>>(Wqkv, Wout, WqkvT, WoutT);
  gemm_bt<__hip_bfloat16, 128, 128><<<dim3(3072 / 128, 4096 / 128), 256, 0, stream>>>(xb, WqkvT, qkv, 4096, 3072, 1024);
  qkv_prep<<<dim3(32, 32), 256, 0, stream>>>(qkv, tab, Q, K, Vt);
  attention<<<1024, 256, 0, stream>>>(Q, K, Vt, attn);
  gemm_bt<float, 64, 64><<<dim3(1024 / 64, 4096 / 64), 256, 0, stream>>>(attn, WoutT, out, 4096, 1024, 1024);
}

// Round 16
// 180.628 us; speedup vs baseline: 1.0531x; 1.0274x over previous
//
#include <hip/hip_runtime.h>
#include <hip/hip_bf16.h>

typedef __attribute__((ext_vector_type(8))) short short8;     // 8 bf16 (MFMA A/B frag, K=32)
typedef __attribute__((ext_vector_type(4))) float float4v;    // MFMA C/D frag

// ---------------------------------------------------------------------------
// prep_all: all input prep in ONE launch (was cvt_and_table + prep_weights).
//   blocks [0,4096):     x fp32 -> xb bf16 (float4 vectorized)
//   blocks [4096,4352):  RoPE table tab[s][p] = (cos,sin), 512 KB, L2-resident
//   blocks [4352,7424):  Wqkv (1024x3072) -> WqkvT (3072x1024) bf16 transpose
//   blocks [7424,8448):  Wout (1024x1024) -> WoutT transpose
// ---------------------------------------------------------------------------
__global__ __launch_bounds__(256) void prep_all(
    const float* __restrict__ x, __hip_bfloat16* __restrict__ xb,
    float2* __restrict__ tab,
    const float* __restrict__ Wqkv, const float* __restrict__ Wout,
    __hip_bfloat16* __restrict__ WqkvT, __hip_bfloat16* __restrict__ WoutT) {
  __shared__ __hip_bfloat16 tile[32][33];
  const int id = blockIdx.x;
  if (id < 4096) {
    const int i = id * 256 + threadIdx.x;
    const float4 v = *(const float4*)(x + (size_t)i * 4);
    __hip_bfloat16 o[4];
    o[0] = __float2bfloat16(v.x); o[1] = __float2bfloat16(v.y);
    o[2] = __float2bfloat16(v.z); o[3] = __float2bfloat16(v.w);
    *(uint2*)(xb + (size_t)i * 4) = *(const uint2*)o;
    return;
  }
  if (id < 4352) {
    const int i = (id - 4096) * 256 + threadIdx.x;   // 65536
    const int s = i >> 5, p = i & 31;
    const float freq = powf(10000.f, -(float)(p * 2) / 64.f);
    float sn, cs;
    sincosf((float)s * freq, &sn, &cs);
    tab[i] = make_float2(cs, sn);
    return;
  }
  const float* in;
  __hip_bfloat16* out;
  int C, bx, by;
  if (id < 7424) {
    const int lid = id - 4352;
    in = Wqkv; out = WqkvT; C = 3072; bx = lid % 96; by = lid / 96;
  } else {
    const int lid = id - 7424;
    in = Wout; out = WoutT; C = 1024; bx = lid & 31; by = lid >> 5;
  }
  const int R = 1024;
  const int c0 = bx * 32, r0 = by * 32;
  const int tx = threadIdx.x & 31, ty = threadIdx.x >> 5;  // ty 0..7
  #pragma unroll
  for (int i = ty; i < 32; i += 8)
    tile[i][tx] = __float2bfloat16(in[(size_t)(r0 + i) * C + (c0 + tx)]);
  __syncthreads();
  #pragma unroll
  for (int i = ty; i < 32; i += 8)
    out[(size_t)(c0 + i) * R + (r0 + tx)] = tile[tx][i];
}

// ---------------------------------------------------------------------------
// gemm_bt: C (MxN, OutT) = A (MxK, row-major bf16) @ Bt^T  (Bt is NxK bf16)
// BMxBN tile, BK=64, 256 threads = 4 waves. Single-buffer r6/r12 K-loop —
// the measured optimum: dbuf (r13) cost occupancy > drain savings; BM=64
// (r15) halved MFMA:staging for nothing. global_load_lds width=16 staging,
// stride-64 LDS + XOR chunk swizzle (r6-verified).
// gemm1: <bf16,128,128> (768 blocks); gemm2: <float,128,64> (512 blocks).
// ---------------------------------------------------------------------------
template <typename OutT, int BM, int BN>
__global__ __launch_bounds__(256) void gemm_bt(
    const __hip_bfloat16* __restrict__ A,
    const __hip_bfloat16* __restrict__ Bt,
    OutT* __restrict__ C,
    int M, int N, int K) {
  __shared__ __hip_bfloat16 lA[BM][64];
  __shared__ __hip_bfloat16 lB[BN][64];
  constexpr int NI = BM / 32, NJ = BN / 32;      // 16-row/col tiles per wave
  const int t = threadIdx.x;
  const int lane = t & 63, wave = t >> 6;
  const int quad = lane >> 4, ln = lane & 15;
  const int m0 = blockIdx.y * BM, n0 = blockIdx.x * BN;
  const int wm = (wave >> 1) * (BM / 2), wn = (wave & 1) * (BN / 2);
  const int srow = lane >> 3;                    // 0..7
  const int schunk = ((lane & 7) ^ srow) * 8;    // swizzled elem offset

  float4v acc[NI][NJ];
  #pragma unroll
  for (int i = 0; i < NI; ++i)
    #pragma unroll
    for (int j = 0; j < NJ; ++j)
      acc[i][j] = (float4v){0.f, 0.f, 0.f, 0.f};

  for (int kt = 0; kt < K; kt += 64) {
    __syncthreads();   // previous iter's frag reads done before DMA overwrite
    #pragma unroll
    for (int g = 0; g < BM / 32; ++g) {
      const int rbase = wave * (BM / 4) + g * 8;
      __builtin_amdgcn_global_load_lds(
          (const __attribute__((address_space(1))) void*)
              (A + (size_t)(m0 + rbase + srow) * K + kt + schunk),
          (__attribute__((address_space(3))) void*)&lA[rbase][0], 16, 0, 0);
    }
    #pragma unroll
    for (int g = 0; g < BN / 32; ++g) {
      const int rbase = wave * (BN / 4) + g * 8;
      __builtin_amdgcn_global_load_lds(
          (const __attribute__((address_space(1))) void*)
              (Bt + (size_t)(n0 + rbase + srow) * K + kt + schunk),
          (__attribute__((address_space(3))) void*)&lB[rbase][0], 16, 0, 0);
    }
    __syncthreads();   // vmcnt(0) drain: DMA complete, LDS visible
    #pragma unroll
    for (int step = 0; step < 2; ++step) {
      short8 af[NI], bf[NJ];
      #pragma unroll
      for (int i = 0; i < NI; ++i)
        af[i] = *(const short8*)&lA[wm + i * 16 + ln][((step * 4 + quad) ^ (ln & 7)) * 8];
      #pragma unroll
      for (int j = 0; j < NJ; ++j)
        bf[j] = *(const short8*)&lB[wn + j * 16 + ln][((step * 4 + quad) ^ (ln & 7)) * 8];
      #pragma unroll
      for (int i = 0; i < NI; ++i)
        #pragma unroll
        for (int j = 0; j < NJ; ++j)
          acc[i][j] = __builtin_amdgcn_mfma_f32_16x16x32_bf16(af[i], bf[j], acc[i][j], 0, 0, 0);
    }
  }
  // Epilogue. C/D layout: row = quad*4 + reg, col = lane&15 (m89/m91-verified).
  #pragma unroll
  for (int i = 0; i < NI; ++i)
    #pragma unroll
    for (int j = 0; j < NJ; ++j)
      #pragma unroll
      for (int r = 0; r < 4; ++r) {
        const int row = m0 + wm + i * 16 + quad * 4 + r;
        const int col = n0 + wn + j * 16 + ln;
        if constexpr (__is_same(OutT, float))
          C[(size_t)row * N + col] = acc[i][j][r];
        else
          C[(size_t)row * N + col] = __float2bfloat16(acc[i][j][r]);
      }
}

// ---------------------------------------------------------------------------
// Fused QKV prep (table-driven, r12 form): rope(Q,K) reshape + V transpose,
// one qkv pass, zero transcendentals. Q scaled by (1/8)*log2(e).
// ---------------------------------------------------------------------------
__global__ __launch_bounds__(256) void qkv_prep(
    const __hip_bfloat16* __restrict__ qkv,
    const float2* __restrict__ tab,
    __hip_bfloat16* __restrict__ Q,
    __hip_bfloat16* __restrict__ K,
    __hip_bfloat16* __restrict__ Vt) {
  __shared__ __hip_bfloat16 tile[64][65];
  const int s0 = blockIdx.x * 64;
  const int bh = blockIdx.y;
  const int h = bh & 15, b = bh >> 4;
  const int t = threadIdx.x;

  const int pr = t & 31, sl = t >> 5;
  const int d0 = pr * 2;
  const float qs = 0.125f * 1.44269504088896340736f;  // (1/8)*log2(e)
  #pragma unroll
  for (int ss = sl; ss < 64; ss += 8) {
    const int s = s0 + ss;
    const float2 cssn = tab[(size_t)s * 32 + pr];
    const float cs = cssn.x, sn = cssn.y;
    const size_t in_base = (size_t)(b * 2048 + s) * 3072;
    const size_t o = ((size_t)bh * 2048 + s) * 64 + d0;

    __hip_bfloat162 q2 = *(const __hip_bfloat162*)&qkv[in_base + h * 64 + d0];
    float x1 = __bfloat162float(q2.x), x2 = __bfloat162float(q2.y);
    __hip_bfloat162 qo;
    qo.x = __float2bfloat16((x1 * cs - x2 * sn) * qs);
    qo.y = __float2bfloat16((x1 * sn + x2 * cs) * qs);
    *(__hip_bfloat162*)&Q[o] = qo;

    __hip_bfloat162 k2 = *(const __hip_bfloat162*)&qkv[in_base + 1024 + h * 64 + d0];
    x1 = __bfloat162float(k2.x); x2 = __bfloat162float(k2.y);
    __hip_bfloat162 ko;
    ko.x = __float2bfloat16(x1 * cs - x2 * sn);
    ko.y = __float2bfloat16(x1 * sn + x2 * cs);
    *(__hip_bfloat162*)&K[o] = ko;
  }

  const int tx = t & 63, ty = t >> 6;  // ty 0..3
  #pragma unroll
  for (int i = ty; i < 64; i += 4)
    tile[i][tx] = qkv[(size_t)(b * 2048 + s0 + i) * 3072 + 2048 + h * 64 + tx];
  __syncthreads();
  #pragma unroll
  for (int i = ty; i < 64; i += 4)
    Vt[((size_t)bh * 64 + i) * 2048 + s0 + tx] = tile[tx][i];
}

// ---------------------------------------------------------------------------
// Flash-style causal attention — FROZEN at the r7/r11 form (~47 µs floor:
// DS-count r9, LDS-BW r10, TLP r11 all falsified; floor is the per-iter
// VALU chain of 16 quarter-rate v_exp_f32 + cvt, invariant across layouts).
// ---------------------------------------------------------------------------
__global__ __launch_bounds__(256) void attention(
    const __hip_bfloat16* __restrict__ Q,
    const __hip_bfloat16* __restrict__ K,
    const __hip_bfloat16* __restrict__ Vt,
    __hip_bfloat16* __restrict__ attn) {
  __shared__ __hip_bfloat16 lK[2][64][64];    // [buf][sk][d]   XOR-swizzled
  __shared__ __hip_bfloat16 lV[2][64][64];    // [buf][d][sk]   XOR-swizzled
  __shared__ __hip_bfloat16 lP[4][16][72];    // per-wave [q][sk]
  const int t = threadIdx.x;
  const int lane = t & 63, w = t >> 6;
  const int quad = lane >> 4, ln = lane & 15;
  const int id = blockIdx.x;
  const int bh = id & 31;                     // fast index -> XCD spread
  const int qt = 31 - (id >> 5);              // longest q-tiles first
  const int q0 = qt * 64;
  const size_t base = (size_t)bh * 2048 * 64;
  const __hip_bfloat16* Qb = Q + base;
  const __hip_bfloat16* Kb = K + base;
  const __hip_bfloat16* Vb = Vt + base;
  const int b = bh >> 4, h = bh & 15;

  short8 ones;
  #pragma unroll
  for (int i = 0; i < 8; ++i) ones[i] = (short)0x3F80;   // bf16 1.0

  const int srow = lane >> 3;
  const int schunk = ((lane & 7) ^ srow) * 8;
  const int rb0 = w * 16;

  #pragma unroll
  for (int g = 0; g < 2; ++g) {
    const int rbase = rb0 + g * 8;
    __builtin_amdgcn_global_load_lds(
        (const __attribute__((address_space(1))) void*)
            (Kb + (size_t)(rbase + srow) * 64 + schunk),
        (__attribute__((address_space(3))) void*)&lK[0][rbase][0], 16, 0, 0);
    __builtin_amdgcn_global_load_lds(
        (const __attribute__((address_space(1))) void*)
            (Vb + (size_t)(rbase + srow) * 2048 + schunk),
        (__attribute__((address_space(3))) void*)&lV[0][rbase][0], 16, 0, 0);
  }

  short8 qf[2];
  {
    const size_t qrow = (size_t)(q0 + w * 16 + ln) * 64;
    qf[0] = *(const short8*)(Qb + qrow + quad * 8);
    qf[1] = *(const short8*)(Qb + qrow + 32 + quad * 8);
  }

  float4v acc_o[4];
  #pragma unroll
  for (int dt = 0; dt < 4; ++dt) acc_o[dt] = (float4v){0.f, 0.f, 0.f, 0.f};
  float4v acc_l = (float4v){0.f, 0.f, 0.f, 0.f};

  for (int kt = 0; kt <= qt; ++kt) {
    const int buf = kt & 1;
    __syncthreads();

    if (kt < qt) {
      #pragma unroll
      for (int g = 0; g < 2; ++g) {
        const int rbase = rb0 + g * 8;
        __builtin_amdgcn_global_load_lds(
            (const __attribute__((address_space(1))) void*)
                (Kb + (size_t)((kt + 1) * 64 + rbase + srow) * 64 + schunk),
            (__attribute__((address_space(3))) void*)&lK[buf ^ 1][rbase][0], 16, 0, 0);
        __builtin_amdgcn_global_load_lds(
            (const __attribute__((address_space(1))) void*)
                (Vb + (size_t)(rbase + srow) * 2048 + (kt + 1) * 64 + schunk),
            (__attribute__((address_space(3))) void*)&lV[buf ^ 1][rbase][0], 16, 0, 0);
      }
    }

    float4v s4[4];
    #pragma unroll
    for (int nt = 0; nt < 4; ++nt) {
      float4v a = (float4v){0.f, 0.f, 0.f, 0.f};
      #pragma unroll
      for (int step = 0; step < 2; ++step) {
        short8 kf = *(const short8*)&lK[buf][nt * 16 + ln][((step * 4 + quad) ^ (ln & 7)) * 8];
        a = __builtin_amdgcn_mfma_f32_16x16x32_bf16(qf[step], kf, a, 0, 0, 0);
      }
      s4[nt] = a;
    }
    if (kt == qt) {
      #pragma unroll
      for (int nt = 0; nt < 4; ++nt)
        #pragma unroll
        for (int r = 0; r < 4; ++r) {
          const int sk = kt * 64 + nt * 16 + ln;
          const int qr = q0 + w * 16 + quad * 4 + r;
          if (sk > qr) s4[nt][r] = -64.f;
        }
    }
    #pragma unroll
    for (int nt = 0; nt < 4; ++nt)
      #pragma unroll
      for (int r = 0; r < 4; ++r)
        lP[w][quad * 4 + r][nt * 16 + ln] = __float2bfloat16(exp2f(s4[nt][r]));
    #pragma unroll
    for (int step = 0; step < 2; ++step) {
      short8 pf = *(const short8*)&lP[w][ln][step * 32 + quad * 8];
      acc_l = __builtin_amdgcn_mfma_f32_16x16x32_bf16(pf, ones, acc_l, 0, 0, 0);
      #pragma unroll
      for (int dt = 0; dt < 4; ++dt) {
        short8 vf = *(const short8*)&lV[buf][dt * 16 + ln][((step * 4 + quad) ^ (ln & 7)) * 8];
        acc_o[dt] = __builtin_amdgcn_mfma_f32_16x16x32_bf16(pf, vf, acc_o[dt], 0, 0, 0);
      }
    }
  }

  float inv_l[4];
  #pragma unroll
  for (int r = 0; r < 4; ++r) inv_l[r] = 1.0f / acc_l[r];
  #pragma unroll
  for (int dt = 0; dt < 4; ++dt)
    #pragma unroll
    for (int r = 0; r < 4; ++r) {
      const int qr = q0 + w * 16 + quad * 4 + r;
      const size_t rg = (size_t)(b * 2048 + qr);
      const int col = h * 64 + dt * 16 + ln;
      attn[rg * 1024 + col] = __float2bfloat16(acc_o[dt][r] * inv_l[r]);
    }
}

// ---------------------------------------------------------------------------
extern "C" void kernel_launch(void* const* d_in, const int* in_sizes, int n_in,
                              void* d_out, int out_size, void* d_ws, size_t ws_size,
                              hipStream_t stream) {
  const float* x    = (const float*)d_in[0];  // (2,2048,1024) fp32
  const float* Wqkv = (const float*)d_in[1];  // (1024,3072)   fp32
  const float* Wout = (const float*)d_in[2];  // (1024,1024)   fp32
  float* out = (float*)d_out;                 // (2,2048,1024) fp32

  __hip_bfloat16* ws = (__hip_bfloat16*)d_ws;
  __hip_bfloat16* xb    = ws;                          // 4096*1024
  __hip_bfloat16* WqkvT = xb    + (size_t)4096 * 1024; // 3072*1024
  __hip_bfloat16* WoutT = WqkvT + (size_t)3072 * 1024; // 1024*1024
  __hip_bfloat16* qkv   = WoutT + (size_t)1024 * 1024; // 4096*3072
  __hip_bfloat16* Q     = qkv   + (size_t)4096 * 3072; // 32*2048*64
  __hip_bfloat16* K     = Q     + (size_t)32 * 2048 * 64;
  __hip_bfloat16* Vt    = K     + (size_t)32 * 2048 * 64;
  __hip_bfloat16* attn  = Vt    + (size_t)32 * 2048 * 64;  // dedicated
  float2*         tab   = (float2*)(attn + (size_t)4096 * 1024);  // 2048x32

  prep_all<<<8448, 256, 0, stream>>>(x, xb, tab, Wqkv, Wout, WqkvT, WoutT);
  gemm_bt<__hip_bfloat16, 128, 128><<<dim3(3072 / 128, 4096 / 128), 256, 0, stream>>>(xb, WqkvT, qkv, 4096, 3072, 1024);
  qkv_prep<<<dim3(32, 32), 256, 0, stream>>>(qkv, tab, Q, K, Vt);
  attention<<<1024, 256, 0, stream>>>(Q, K, Vt, attn);
  gemm_bt<float, 128, 64><<<dim3(1024 / 64, 4096 / 128), 256, 0, stream>>>(attn, WoutT, out, 4096, 1024, 1024);
}